// Round 1
// baseline (58.889 us; speedup 1.0000x reference)
//
#include <hip/hip_runtime.h>

#define NBATCH 256
#define NCH 30
#define LAMBDA_COORD 5.0f
#define LAMBDA_NOOBJ 0.5f

__global__ __launch_bounds__(256) void yolo_loss_kernel(
    const float* __restrict__ pred,
    const float* __restrict__ targ,
    float* __restrict__ out,
    int n4)
{
    float acc = 0.0f;
    const int stride = gridDim.x * blockDim.x;
    const float4* __restrict__ p4 = reinterpret_cast<const float4*>(pred);
    const float4* __restrict__ t4 = reinterpret_cast<const float4*>(targ);

    for (int i = blockIdx.x * blockDim.x + threadIdx.x; i < n4; i += stride) {
        float4 pv = p4[i];
        float4 tv = t4[i];
        int base = i * 4;
        float pe[4] = {pv.x, pv.y, pv.z, pv.w};
        float te[4] = {tv.x, tv.y, tv.z, tv.w};
        #pragma unroll
        for (int k = 0; k < 4; ++k) {
            int idx  = base + k;
            int cell = idx / NCH;          // compiler -> magic-mul
            int c    = idx - cell * NCH;
            float p = pe[k];
            float t = te[k];
            // objectness of this cell (L1-hit scalar load; reuse t when c==4)
            float tconf = (c == 4) ? t : targ[cell * NCH + 4];
            float obj = (tconf == 1.0f) ? 1.0f : 0.0f;
            float d = (c == 2 || c == 3) ? (sqrtf(p) - sqrtf(t)) : (p - t);
            float sq = d * d;
            float w;
            if (c < 4)       w = LAMBDA_COORD * obj;
            else if (c == 4) w = obj + LAMBDA_NOOBJ * (1.0f - obj);
            else             w = obj;
            acc += w * sq;
        }
    }

    // wave64 shuffle reduction
    #pragma unroll
    for (int off = 32; off > 0; off >>= 1)
        acc += __shfl_down(acc, off, 64);

    __shared__ float lds[4];
    int lane = threadIdx.x & 63;
    int wid  = threadIdx.x >> 6;
    if (lane == 0) lds[wid] = acc;
    __syncthreads();
    if (threadIdx.x == 0) {
        float s = lds[0] + lds[1] + lds[2] + lds[3];
        atomicAdd(out, s * (1.0f / (float)NBATCH));
    }
}

extern "C" void kernel_launch(void* const* d_in, const int* in_sizes, int n_in,
                              void* d_out, int out_size, void* d_ws, size_t ws_size,
                              hipStream_t stream)
{
    const float* pred = (const float*)d_in[0];
    const float* targ = (const float*)d_in[1];
    float* out = (float*)d_out;

    // zero the accumulator (harness poisons once, never re-poisons between replays)
    hipMemsetAsync(out, 0, sizeof(float), stream);

    int n  = in_sizes[0];          // 256*56*56*30 = 24,084,480 (divisible by 4)
    int n4 = n / 4;

    int blocks = 2048;             // grid-stride; ~11.5 float4 per thread
    yolo_loss_kernel<<<blocks, 256, 0, stream>>>(pred, targ, out, n4);
}